// Round 1
// baseline (4703.036 us; speedup 1.0000x reference)
//
#include <hip/hip_runtime.h>

#define BN 4096     // batch
#define DF 784
#define HALFF 392
#define HIDF 512
#define NBLK 20

typedef _Float16 f16;
typedef _Float16 half2v __attribute__((ext_vector_type(2)));
typedef _Float16 half4v __attribute__((ext_vector_type(4)));
typedef _Float16 half8v __attribute__((ext_vector_type(8)));
typedef float    fx4    __attribute__((ext_vector_type(4)));

// ---------------------------------------------------------------------------
// GEMM1: H[n][b] = relu( sum_{k<392} W[k][n] * A[k][b] + W[392+l[b]][n] + bias[n] )
// A[k][b] = Vsrc[rowmap ? rowmap[k] : k][b]   (fp32 -> fp16 on staging)
// W: (402 x 512) fp32 row-major.  H: (512 x 4096) fp16.
// grid (8, 32), block 256.
// ---------------------------------------------------------------------------
__global__ __launch_bounds__(256)
void gemm1_k(const float* __restrict__ Vsrc, const int* __restrict__ rowmap,
             const float* __restrict__ W, const float* __restrict__ bias,
             const int* __restrict__ lvec, f16* __restrict__ Hout)
{
    __shared__ __align__(16) f16 Wl[64][40];
    __shared__ __align__(16) f16 Al[128][40];

    const int tid  = threadIdx.x;
    const int n0   = blockIdx.x * 64;
    const int b0   = blockIdx.y * 128;
    const int wid  = tid >> 6, lane = tid & 63;
    const int wn   = wid >> 1, wb = wid & 1;
    const int ln16 = lane & 15, koct = lane >> 4;

    fx4 acc[2][4];
    #pragma unroll
    for (int i = 0; i < 2; i++)
        #pragma unroll
        for (int j = 0; j < 4; j++) acc[i][j] = (fx4)0.f;

    const int kpW = tid >> 4;          // 0..15  (pairs of k rows for W)
    const int nqW = (tid & 15) * 4;    // n quad
    const int kpA = tid >> 5;          // 0..7   (pairs of k rows for A)
    const int bqA = (tid & 31) * 4;    // b quad

    for (int k0 = 0; k0 < HALFF; k0 += 32) {
        __syncthreads();
        // ---- stage W tile (32k x 64n), transposed to Wl[n][k], fp16
        {
            int ka = k0 + 2 * kpW, kb = ka + 1;
            fx4 wa = (ka < HALFF) ? *(const fx4*)&W[(long)ka * HIDF + n0 + nqW] : (fx4)0.f;
            fx4 wb2 = (kb < HALFF) ? *(const fx4*)&W[(long)kb * HIDF + n0 + nqW] : (fx4)0.f;
            #pragma unroll
            for (int j = 0; j < 4; j++) {
                half2v p; p[0] = (f16)wa[j]; p[1] = (f16)wb2[j];
                *(half2v*)&Wl[nqW + j][2 * kpW] = p;
            }
        }
        // ---- stage A tile (32k x 128b), transposed to Al[b][k], fp16
        #pragma unroll
        for (int p = 0; p < 2; p++) {
            int kp = kpA + p * 8;
            int ka = k0 + 2 * kp, kb = ka + 1;
            fx4 xa = (fx4)0.f, xb = (fx4)0.f;
            if (ka < HALFF) {
                int ra = rowmap ? rowmap[ka] : ka;
                xa = *(const fx4*)&Vsrc[(long)ra * BN + b0 + bqA];
            }
            if (kb < HALFF) {
                int rb = rowmap ? rowmap[kb] : kb;
                xb = *(const fx4*)&Vsrc[(long)rb * BN + b0 + bqA];
            }
            #pragma unroll
            for (int j = 0; j < 4; j++) {
                half2v p; p[0] = (f16)xa[j]; p[1] = (f16)xb[j];
                *(half2v*)&Al[bqA + j][2 * kp] = p;
            }
        }
        __syncthreads();
        // ---- fragments + MFMA
        half8v af[2], bf[4];
        #pragma unroll
        for (int ni = 0; ni < 2; ni++)
            af[ni] = *(const half8v*)&Wl[wn * 32 + ni * 16 + ln16][koct * 8];
        #pragma unroll
        for (int bi = 0; bi < 4; bi++)
            bf[bi] = *(const half8v*)&Al[wb * 64 + bi * 16 + ln16][koct * 8];
        #pragma unroll
        for (int ni = 0; ni < 2; ni++)
            #pragma unroll
            for (int bi = 0; bi < 4; bi++)
                acc[ni][bi] = __builtin_amdgcn_mfma_f32_16x16x32_f16(af[ni], bf[bi], acc[ni][bi], 0, 0, 0);
    }

    // ---- epilogue: + bias + cond row, relu, fp16 store
    #pragma unroll
    for (int ni = 0; ni < 2; ni++) {
        int nb = n0 + wn * 32 + ni * 16 + koct * 4;
        #pragma unroll
        for (int bi = 0; bi < 4; bi++) {
            int b = b0 + wb * 64 + bi * 16 + ln16;
            int lv = lvec[b];
            const float* crow = &W[(long)(HALFF + lv) * HIDF];
            #pragma unroll
            for (int r = 0; r < 4; r++) {
                int n = nb + r;
                float v = acc[ni][bi][r] + bias[n] + crow[n];
                v = fmaxf(v, 0.f);
                Hout[(long)n * BN + b] = (f16)v;
            }
        }
    }
}

// ---------------------------------------------------------------------------
// GEMM2: R[n][b] = sum_{k<512} W[k][n] * H[k][b] + bias[n]
// W: (512 x 784) fp32. H: (512 x 4096) fp16. R: (784 x 4096) fp32.
// grid (13, 32), block 256.
// ---------------------------------------------------------------------------
__global__ __launch_bounds__(256)
void gemm2_k(const f16* __restrict__ Hin, const float* __restrict__ W,
             const float* __restrict__ bias, float* __restrict__ Rout)
{
    __shared__ __align__(16) f16 Wl[64][40];
    __shared__ __align__(16) f16 Al[128][40];

    const int tid  = threadIdx.x;
    const int n0   = blockIdx.x * 64;
    const int b0   = blockIdx.y * 128;
    const int wid  = tid >> 6, lane = tid & 63;
    const int wn   = wid >> 1, wb = wid & 1;
    const int ln16 = lane & 15, koct = lane >> 4;

    fx4 acc[2][4];
    #pragma unroll
    for (int i = 0; i < 2; i++)
        #pragma unroll
        for (int j = 0; j < 4; j++) acc[i][j] = (fx4)0.f;

    const int kpW = tid >> 4;
    const int nqW = (tid & 15) * 4;
    const int kpA = tid >> 5;
    const int bqA = (tid & 31) * 4;

    for (int k0 = 0; k0 < HIDF; k0 += 32) {
        __syncthreads();
        // ---- stage W tile
        {
            int ka = k0 + 2 * kpW, kb = ka + 1;
            bool nok = (n0 + nqW) < DF;
            fx4 wa = nok ? *(const fx4*)&W[(long)ka * DF + n0 + nqW] : (fx4)0.f;
            fx4 wb2 = nok ? *(const fx4*)&W[(long)kb * DF + n0 + nqW] : (fx4)0.f;
            #pragma unroll
            for (int j = 0; j < 4; j++) {
                half2v p; p[0] = (f16)wa[j]; p[1] = (f16)wb2[j];
                *(half2v*)&Wl[nqW + j][2 * kpW] = p;
            }
        }
        // ---- stage A tile from fp16 H
        #pragma unroll
        for (int p = 0; p < 2; p++) {
            int kp = kpA + p * 8;
            int ka = k0 + 2 * kp, kb = ka + 1;
            half4v ha = *(const half4v*)&Hin[(long)ka * BN + b0 + bqA];
            half4v hb = *(const half4v*)&Hin[(long)kb * BN + b0 + bqA];
            #pragma unroll
            for (int j = 0; j < 4; j++) {
                half2v p; p[0] = ha[j]; p[1] = hb[j];
                *(half2v*)&Al[bqA + j][2 * kp] = p;
            }
        }
        __syncthreads();
        half8v af[2], bf[4];
        #pragma unroll
        for (int ni = 0; ni < 2; ni++)
            af[ni] = *(const half8v*)&Wl[wn * 32 + ni * 16 + ln16][koct * 8];
        #pragma unroll
        for (int bi = 0; bi < 4; bi++)
            bf[bi] = *(const half8v*)&Al[wb * 64 + bi * 16 + ln16][koct * 8];
        #pragma unroll
        for (int ni = 0; ni < 2; ni++)
            #pragma unroll
            for (int bi = 0; bi < 4; bi++)
                acc[ni][bi] = __builtin_amdgcn_mfma_f32_16x16x32_f16(af[ni], bf[bi], acc[ni][bi], 0, 0, 0);
    }

    #pragma unroll
    for (int ni = 0; ni < 2; ni++) {
        int nb = n0 + wn * 32 + ni * 16 + koct * 4;
        #pragma unroll
        for (int bi = 0; bi < 4; bi++) {
            int b = b0 + wb * 64 + bi * 16 + ln16;
            #pragma unroll
            for (int r = 0; r < 4; r++) {
                int n = nb + r;
                if (n < DF)
                    Rout[(long)n * BN + b] = acc[ni][bi][r] + bias[n];
            }
        }
    }
}

// ---------------------------------------------------------------------------
// Coupling: y[d][b] = exp(ls)*x[d][b] + R[392+d][b],  ls = 0.636*atan(R[d][b])
// x[d][b] = Vcur[permRow[d]][b].  jac[b] += sum_d ls.
// grid 64, block 256 (64 b-lanes x 4 d-groups).
// ---------------------------------------------------------------------------
__global__ __launch_bounds__(256)
void couple_k(const float* __restrict__ R, const float* __restrict__ Vcur,
              const int* __restrict__ permRow, float* __restrict__ Vdst,
              float* __restrict__ jac)
{
    __shared__ float red[4][64];
    const int t  = threadIdx.x;
    const int bl = t & 63;
    const int tg = t >> 6;
    const int b  = blockIdx.x * 64 + bl;

    float jp = 0.f;
    for (int d = tg; d < HALFF; d += 4) {
        float s  = R[(long)d * BN + b];
        float tt = R[(long)(d + HALFF) * BN + b];
        float x  = Vcur[(long)permRow[d] * BN + b];
        float ls = 0.636f * atanf(s);
        jp += ls;
        Vdst[(long)d * BN + b] = expf(ls) * x + tt;
    }
    red[tg][bl] = jp;
    __syncthreads();
    if (tg == 0)
        jac[b] += red[0][bl] + red[1][bl] + red[2][bl] + red[3][bl];
}

// ---------------------------------------------------------------------------
// transposes + jac helpers
// ---------------------------------------------------------------------------
__global__ void tin_k(const float* __restrict__ x, float* __restrict__ V)
{
    __shared__ float tile[32][33];
    int tx = threadIdx.x, ty = threadIdx.y;
    int d0 = blockIdx.x * 32, b0 = blockIdx.y * 32;
    #pragma unroll
    for (int j = 0; j < 4; j++) {
        int d = d0 + tx, b = b0 + ty + j * 8;
        tile[ty + j * 8][tx] = (d < DF) ? x[(long)b * DF + d] : 0.f;
    }
    __syncthreads();
    #pragma unroll
    for (int j = 0; j < 4; j++) {
        int d = d0 + ty + j * 8, b = b0 + tx;
        if (d < DF) V[(long)d * BN + b] = tile[tx][ty + j * 8];
    }
}

__global__ void tout_k(const float* __restrict__ V, float* __restrict__ z)
{
    __shared__ float tile[32][33];
    int tx = threadIdx.x, ty = threadIdx.y;
    int d0 = blockIdx.x * 32, b0 = blockIdx.y * 32;
    #pragma unroll
    for (int j = 0; j < 4; j++) {
        int d = d0 + ty + j * 8, b = b0 + tx;
        tile[ty + j * 8][tx] = (d < DF) ? V[(long)d * BN + b] : 0.f;
    }
    __syncthreads();
    #pragma unroll
    for (int j = 0; j < 4; j++) {
        int b = b0 + ty + j * 8, d = d0 + tx;
        if (d < DF) z[(long)b * DF + d] = tile[tx][ty + j * 8];
    }
}

__global__ void zero_k(float* __restrict__ p)
{
    p[blockIdx.x * 256 + threadIdx.x] = 0.f;
}

__global__ void cjac_k(const float* __restrict__ jac, float* __restrict__ out)
{
    int i = blockIdx.x * 256 + threadIdx.x;
    out[i] = jac[i];
}

// ---------------------------------------------------------------------------
extern "C" void kernel_launch(void* const* d_in, const int* in_sizes, int n_in,
                              void* d_out, int out_size, void* d_ws, size_t ws_size,
                              hipStream_t stream)
{
    const float* x     = (const float*)d_in[0];
    const int*   l     = (const int*)d_in[1];
    const int*   perms = (const int*)d_in[2];
    const float* s1W1  = (const float*)d_in[3];
    const float* s1b1  = (const float*)d_in[4];
    const float* s1W2  = (const float*)d_in[5];
    const float* s1b2  = (const float*)d_in[6];
    const float* s2W1  = (const float*)d_in[7];
    const float* s2b1  = (const float*)d_in[8];
    const float* s2W2  = (const float*)d_in[9];
    const float* s2b2  = (const float*)d_in[10];
    float* out = (float*)d_out;

    char* ws = (char*)d_ws;
    const size_t VBYTES = (size_t)DF * BN * 4;       // 12,845,056
    float* Va  = (float*)(ws);
    float* Vb  = (float*)(ws + VBYTES);
    f16*   H   = (f16*)  (ws + 2 * VBYTES);          // 512*4096*2 = 4 MB
    float* R   = (float*)(ws + 2 * VBYTES + (size_t)HIDF * BN * 2);
    float* jac = (float*)(ws + 3 * VBYTES + (size_t)HIDF * BN * 2);

    tin_k<<<dim3(25, 128), dim3(32, 8), 0, stream>>>(x, Va);
    zero_k<<<16, 256, 0, stream>>>(jac);

    float* Vc = Va;
    float* Vn = Vb;
    for (int i = 0; i < NBLK; i++) {
        const int* perm = perms + (long)i * DF;
        // substep 2: r2 = f2([x2, c]);  y1 = exp(ls2)*x1 + t2
        gemm1_k<<<dim3(8, 32), 256, 0, stream>>>(Vc, perm + HALFF,
                s2W1 + (long)i * 402 * 512, s2b1 + (long)i * 512, l, H);
        gemm2_k<<<dim3(13, 32), 256, 0, stream>>>(H,
                s2W2 + (long)i * 512 * 784, s2b2 + (long)i * 784, R);
        couple_k<<<64, 256, 0, stream>>>(R, Vc, perm, Vn, jac);
        // substep 1: r1 = f1([y1, c]);  y2 = exp(ls1)*x2 + t1
        gemm1_k<<<dim3(8, 32), 256, 0, stream>>>(Vn, nullptr,
                s1W1 + (long)i * 402 * 512, s1b1 + (long)i * 512, l, H);
        gemm2_k<<<dim3(13, 32), 256, 0, stream>>>(H,
                s1W2 + (long)i * 512 * 784, s1b2 + (long)i * 784, R);
        couple_k<<<64, 256, 0, stream>>>(R, Vc, perm + HALFF,
                Vn + (long)HALFF * BN, jac);
        float* tmp = Vc; Vc = Vn; Vn = tmp;
    }

    tout_k<<<dim3(25, 128), dim3(32, 8), 0, stream>>>(Vc, out);
    cjac_k<<<16, 256, 0, stream>>>(jac, out + (long)BN * DF);
}

// Round 2
// 2799.803 us; speedup vs baseline: 1.6798x; 1.6798x over previous
//
#include <hip/hip_runtime.h>

#define BN 4096     // batch
#define DF 784
#define HALFF 392
#define HIDF 512
#define NBLK 20

typedef _Float16 f16;
typedef _Float16 half2v __attribute__((ext_vector_type(2)));
typedef _Float16 half4v __attribute__((ext_vector_type(4)));
typedef _Float16 half8v __attribute__((ext_vector_type(8)));
typedef float    fx4    __attribute__((ext_vector_type(4)));

// ---------------------------------------------------------------------------
// GEMM1: H[n][b] = relu( sum_{k<392} W[k][n] * A[k][b] + W[392+l[b]][n] + bias[n] )
// A[k][b] = Vsrc[rowmap ? rowmap[k] : k][b]   (fp32 -> fp16 on staging)
// W: (402 x 512) fp32 row-major.  H: (512 x 4096) fp16.
// grid (8, 32), block 256.
// ---------------------------------------------------------------------------
__global__ __launch_bounds__(256)
void gemm1_k(const float* __restrict__ Vsrc, const int* __restrict__ rowmap,
             const float* __restrict__ W, const float* __restrict__ bias,
             const int* __restrict__ lvec, f16* __restrict__ Hout)
{
    __shared__ __align__(16) f16 Wl[64][40];
    __shared__ __align__(16) f16 Al[128][40];

    const int tid  = threadIdx.x;
    const int n0   = blockIdx.x * 64;
    const int b0   = blockIdx.y * 128;
    const int wid  = tid >> 6, lane = tid & 63;
    const int wn   = wid >> 1, wb = wid & 1;
    const int ln16 = lane & 15, koct = lane >> 4;

    fx4 acc[2][4];
    #pragma unroll
    for (int i = 0; i < 2; i++)
        #pragma unroll
        for (int j = 0; j < 4; j++) acc[i][j] = (fx4)0.f;

    const int kpW = tid >> 4;          // 0..15  (pairs of k rows for W)
    const int nqW = (tid & 15) * 4;    // n quad
    const int kpA = tid >> 5;          // 0..7   (pairs of k rows for A)
    const int bqA = (tid & 31) * 4;    // b quad

    for (int k0 = 0; k0 < HALFF; k0 += 32) {
        __syncthreads();
        // ---- stage W tile (32k x 64n), transposed to Wl[n][k], fp16
        {
            int ka = k0 + 2 * kpW, kb = ka + 1;
            fx4 wa = (ka < HALFF) ? *(const fx4*)&W[(long)ka * HIDF + n0 + nqW] : (fx4)0.f;
            fx4 wb2 = (kb < HALFF) ? *(const fx4*)&W[(long)kb * HIDF + n0 + nqW] : (fx4)0.f;
            #pragma unroll
            for (int j = 0; j < 4; j++) {
                half2v p; p[0] = (f16)wa[j]; p[1] = (f16)wb2[j];
                *(half2v*)&Wl[nqW + j][2 * kpW] = p;
            }
        }
        // ---- stage A tile (32k x 128b), transposed to Al[b][k], fp16
        #pragma unroll
        for (int p = 0; p < 2; p++) {
            int kp = kpA + p * 8;
            int ka = k0 + 2 * kp, kb = ka + 1;
            fx4 xa = (fx4)0.f, xb = (fx4)0.f;
            if (ka < HALFF) {
                int ra = rowmap ? rowmap[ka] : ka;
                xa = *(const fx4*)&Vsrc[(long)ra * BN + b0 + bqA];
            }
            if (kb < HALFF) {
                int rb = rowmap ? rowmap[kb] : kb;
                xb = *(const fx4*)&Vsrc[(long)rb * BN + b0 + bqA];
            }
            #pragma unroll
            for (int j = 0; j < 4; j++) {
                half2v p; p[0] = (f16)xa[j]; p[1] = (f16)xb[j];
                *(half2v*)&Al[bqA + j][2 * kp] = p;
            }
        }
        __syncthreads();
        // ---- fragments + MFMA
        half8v af[2], bf[4];
        #pragma unroll
        for (int ni = 0; ni < 2; ni++)
            af[ni] = *(const half8v*)&Wl[wn * 32 + ni * 16 + ln16][koct * 8];
        #pragma unroll
        for (int bi = 0; bi < 4; bi++)
            bf[bi] = *(const half8v*)&Al[wb * 64 + bi * 16 + ln16][koct * 8];
        #pragma unroll
        for (int ni = 0; ni < 2; ni++)
            #pragma unroll
            for (int bi = 0; bi < 4; bi++)
                acc[ni][bi] = __builtin_amdgcn_mfma_f32_16x16x32_f16(af[ni], bf[bi], acc[ni][bi], 0, 0, 0);
    }

    // ---- epilogue: + bias + cond row, relu, fp16 store
    #pragma unroll
    for (int ni = 0; ni < 2; ni++) {
        int nb = n0 + wn * 32 + ni * 16 + koct * 4;
        #pragma unroll
        for (int bi = 0; bi < 4; bi++) {
            int b = b0 + wb * 64 + bi * 16 + ln16;
            int lv = lvec[b];
            const float* crow = &W[(long)(HALFF + lv) * HIDF];
            #pragma unroll
            for (int r = 0; r < 4; r++) {
                int n = nb + r;
                float v = acc[ni][bi][r] + bias[n] + crow[n];
                v = fmaxf(v, 0.f);
                Hout[(long)n * BN + b] = (f16)v;
            }
        }
    }
}

// ---------------------------------------------------------------------------
// Fused GEMM2 + coupling.
// For d-tile [d0, d0+32) x b-tile [b0, b0+128):
//   s[d][b] = sum_k W[k][d]     * H[k][b] + bias[d]
//   t[d][b] = sum_k W[k][d+392] * H[k][b] + bias[d+392]
//   ls = 0.636*atan(s);  Vdst[d][b] = exp(ls)*Vcur[permRow[d]][b] + t
//   jac[b] += sum_d ls
// Column remap inside the 64-wide MFMA tile: fragment ni=0 -> s columns,
// ni=1 -> matching t columns, so each lane holds s AND t for the same (d,b).
// grid (13, 32), block 256.
// ---------------------------------------------------------------------------
__global__ __launch_bounds__(256)
void gemm2c_k(const f16* __restrict__ Hin, const float* __restrict__ W,
              const float* __restrict__ bias, const float* __restrict__ Vcur,
              const int* __restrict__ permRow, float* __restrict__ Vdst,
              float* __restrict__ jac)
{
    __shared__ __align__(16) f16 Wl[64][40];
    __shared__ __align__(16) f16 Al[128][40];

    const int tid  = threadIdx.x;
    const int d0   = blockIdx.x * 32;
    const int b0   = blockIdx.y * 128;
    const int wid  = tid >> 6, lane = tid & 63;
    const int wn   = wid >> 1, wb = wid & 1;
    const int ln16 = lane & 15, koct = lane >> 4;

    fx4 acc[2][4];
    #pragma unroll
    for (int i = 0; i < 2; i++)
        #pragma unroll
        for (int j = 0; j < 4; j++) acc[i][j] = (fx4)0.f;

    const int kpW = tid >> 4;          // 0..15
    const int nqW = (tid & 15) * 4;    // n quad within [0,64)
    const int kpA = tid >> 5;          // 0..7
    const int bqA = (tid & 31) * 4;

    // column map for the n quad this thread stages:
    // n = wn_*32 + ni_*16 + q  ->  col = d0 + wn_*16 + q + ni_*392
    const int wn_ = nqW >> 5;
    const int ni_ = (nqW >> 4) & 1;
    const int q_  = nqW & 15;
    const int dq  = d0 + wn_ * 16 + q_;       // d of first elem in quad
    const int colq = dq + ni_ * HALFF;        // W column of first elem
    const bool fullblk = (d0 + 32 <= HALFF);  // blocks 0..11 fully valid

    for (int k0 = 0; k0 < HIDF; k0 += 32) {
        __syncthreads();
        // ---- stage W tile (cols remapped), fp16
        {
            int ka = k0 + 2 * kpW, kb = ka + 1;
            fx4 wa, wb2;
            if (fullblk) {
                wa  = *(const fx4*)&W[(long)ka * DF + colq];
                wb2 = *(const fx4*)&W[(long)kb * DF + colq];
            } else {
                #pragma unroll
                for (int j = 0; j < 4; j++) {
                    bool ok = (dq + j) < HALFF;
                    wa[j]  = ok ? W[(long)ka * DF + colq + j] : 0.f;
                    wb2[j] = ok ? W[(long)kb * DF + colq + j] : 0.f;
                }
            }
            #pragma unroll
            for (int j = 0; j < 4; j++) {
                half2v p; p[0] = (f16)wa[j]; p[1] = (f16)wb2[j];
                *(half2v*)&Wl[nqW + j][2 * kpW] = p;
            }
        }
        // ---- stage A tile from fp16 H
        #pragma unroll
        for (int p = 0; p < 2; p++) {
            int kp = kpA + p * 8;
            int ka = k0 + 2 * kp, kb = ka + 1;
            half4v ha = *(const half4v*)&Hin[(long)ka * BN + b0 + bqA];
            half4v hb = *(const half4v*)&Hin[(long)kb * BN + b0 + bqA];
            #pragma unroll
            for (int j = 0; j < 4; j++) {
                half2v p; p[0] = ha[j]; p[1] = hb[j];
                *(half2v*)&Al[bqA + j][2 * kp] = p;
            }
        }
        __syncthreads();
        half8v af[2], bf[4];
        #pragma unroll
        for (int ni = 0; ni < 2; ni++)
            af[ni] = *(const half8v*)&Wl[wn * 32 + ni * 16 + ln16][koct * 8];
        #pragma unroll
        for (int bi = 0; bi < 4; bi++)
            bf[bi] = *(const half8v*)&Al[wb * 64 + bi * 16 + ln16][koct * 8];
        #pragma unroll
        for (int ni = 0; ni < 2; ni++)
            #pragma unroll
            for (int bi = 0; bi < 4; bi++)
                acc[ni][bi] = __builtin_amdgcn_mfma_f32_16x16x32_f16(af[ni], bf[bi], acc[ni][bi], 0, 0, 0);
    }

    // ---- fused coupling epilogue
    const int dbase = d0 + wn * 16 + koct * 4;
    #pragma unroll
    for (int bi = 0; bi < 4; bi++) {
        int b = b0 + wb * 64 + bi * 16 + ln16;
        float jp = 0.f;
        #pragma unroll
        for (int r = 0; r < 4; r++) {
            int d = dbase + r;
            if (d < HALFF) {
                float s  = acc[0][bi][r] + bias[d];
                float tt = acc[1][bi][r] + bias[d + HALFF];
                float x  = Vcur[(long)permRow[d] * BN + b];
                float ls = 0.636f * atanf(s);
                jp += ls;
                Vdst[(long)d * BN + b] = expf(ls) * x + tt;
            }
        }
        // reduce jp across the 4 koct lanes (same b), one atomic per group
        jp += __shfl_xor(jp, 16);
        jp += __shfl_xor(jp, 32);
        if (koct == 0)
            atomicAdd(&jac[b], jp);
    }
}

// ---------------------------------------------------------------------------
// transposes + jac helpers
// ---------------------------------------------------------------------------
__global__ void tin_k(const float* __restrict__ x, float* __restrict__ V)
{
    __shared__ float tile[32][33];
    int tx = threadIdx.x, ty = threadIdx.y;
    int d0 = blockIdx.x * 32, b0 = blockIdx.y * 32;
    #pragma unroll
    for (int j = 0; j < 4; j++) {
        int d = d0 + tx, b = b0 + ty + j * 8;
        tile[ty + j * 8][tx] = (d < DF) ? x[(long)b * DF + d] : 0.f;
    }
    __syncthreads();
    #pragma unroll
    for (int j = 0; j < 4; j++) {
        int d = d0 + ty + j * 8, b = b0 + tx;
        if (d < DF) V[(long)d * BN + b] = tile[tx][ty + j * 8];
    }
}

__global__ void tout_k(const float* __restrict__ V, float* __restrict__ z)
{
    __shared__ float tile[32][33];
    int tx = threadIdx.x, ty = threadIdx.y;
    int d0 = blockIdx.x * 32, b0 = blockIdx.y * 32;
    #pragma unroll
    for (int j = 0; j < 4; j++) {
        int d = d0 + ty + j * 8, b = b0 + tx;
        tile[ty + j * 8][tx] = (d < DF) ? V[(long)d * BN + b] : 0.f;
    }
    __syncthreads();
    #pragma unroll
    for (int j = 0; j < 4; j++) {
        int b = b0 + ty + j * 8, d = d0 + tx;
        if (d < DF) z[(long)b * DF + d] = tile[tx][ty + j * 8];
    }
}

__global__ void zero_k(float* __restrict__ p)
{
    p[blockIdx.x * 256 + threadIdx.x] = 0.f;
}

__global__ void cjac_k(const float* __restrict__ jac, float* __restrict__ out)
{
    int i = blockIdx.x * 256 + threadIdx.x;
    out[i] = jac[i];
}

// ---------------------------------------------------------------------------
extern "C" void kernel_launch(void* const* d_in, const int* in_sizes, int n_in,
                              void* d_out, int out_size, void* d_ws, size_t ws_size,
                              hipStream_t stream)
{
    const float* x     = (const float*)d_in[0];
    const int*   l     = (const int*)d_in[1];
    const int*   perms = (const int*)d_in[2];
    const float* s1W1  = (const float*)d_in[3];
    const float* s1b1  = (const float*)d_in[4];
    const float* s1W2  = (const float*)d_in[5];
    const float* s1b2  = (const float*)d_in[6];
    const float* s2W1  = (const float*)d_in[7];
    const float* s2b1  = (const float*)d_in[8];
    const float* s2W2  = (const float*)d_in[9];
    const float* s2b2  = (const float*)d_in[10];
    float* out = (float*)d_out;

    char* ws = (char*)d_ws;
    const size_t VBYTES = (size_t)DF * BN * 4;       // 12,845,056
    float* Va  = (float*)(ws);
    float* Vb  = (float*)(ws + VBYTES);
    f16*   H   = (f16*)  (ws + 2 * VBYTES);          // 512*4096*2 = 4 MB
    float* jac = (float*)(ws + 2 * VBYTES + (size_t)HIDF * BN * 2);

    tin_k<<<dim3(25, 128), dim3(32, 8), 0, stream>>>(x, Va);
    zero_k<<<16, 256, 0, stream>>>(jac);

    float* Vc = Va;
    float* Vn = Vb;
    for (int i = 0; i < NBLK; i++) {
        const int* perm = perms + (long)i * DF;
        // substep 2: r2 = f2([x2, c]);  y1 = exp(ls2)*x1 + t2
        gemm1_k<<<dim3(8, 32), 256, 0, stream>>>(Vc, perm + HALFF,
                s2W1 + (long)i * 402 * 512, s2b1 + (long)i * 512, l, H);
        gemm2c_k<<<dim3(13, 32), 256, 0, stream>>>(H,
                s2W2 + (long)i * 512 * 784, s2b2 + (long)i * 784,
                Vc, perm, Vn, jac);
        // substep 1: r1 = f1([y1, c]);  y2 = exp(ls1)*x2 + t1
        gemm1_k<<<dim3(8, 32), 256, 0, stream>>>(Vn, nullptr,
                s1W1 + (long)i * 402 * 512, s1b1 + (long)i * 512, l, H);
        gemm2c_k<<<dim3(13, 32), 256, 0, stream>>>(H,
                s1W2 + (long)i * 512 * 784, s1b2 + (long)i * 784,
                Vc, perm + HALFF, Vn + (long)HALFF * BN, jac);
        float* tmp = Vc; Vc = Vn; Vn = tmp;
    }

    tout_k<<<dim3(25, 128), dim3(32, 8), 0, stream>>>(Vc, out);
    cjac_k<<<16, 256, 0, stream>>>(jac, out + (long)BN * DF);
}